// Round 18
// baseline (68.293 us; speedup 1.0000x reference)
//
#include <hip/hip_runtime.h>
#include <math.h>

#define BB 16
#define NN 96
#define HH 256
#define NBIN 11
#define IB 2       // i's per compute block

typedef float f32x4 __attribute__((ext_vector_type(4)));

// ---------------------------------------------------------------------------
// DPP wave64 sum -> wave-uniform scalar. Pure VALU.
// ---------------------------------------------------------------------------
template <int CTRL>
__device__ __forceinline__ float dpp_add(float x) {
    int t = __builtin_amdgcn_update_dpp(0, __float_as_int(x),
                                        CTRL, 0xf, 0xf, true);
    return x + __int_as_float(t);
}

__device__ __forceinline__ float wave64_sum_uniform(float x) {
    x = dpp_add<0x111>(x);  // row_shr:1
    x = dpp_add<0x112>(x);  // row_shr:2
    x = dpp_add<0x114>(x);  // row_shr:4
    x = dpp_add<0x118>(x);  // row_shr:8
    x = dpp_add<0x142>(x);  // row_bcast:15
    x = dpp_add<0x143>(x);  // row_bcast:31
    return __int_as_float(__builtin_amdgcn_readlane(__float_as_int(x), 63));
}

// ---------------------------------------------------------------------------
// Kernel 1: proj[r][k] = sum_h inputs[r][h] * W_atom[h][k] + 0.5*b_bin[k]
// ---------------------------------------------------------------------------
#define ROWS_PER_BLOCK 3

__global__ __launch_bounds__(HH) void proj_kernel(
    const float* __restrict__ inputs,
    const float* __restrict__ W_atom,
    const float* __restrict__ b_bin,
    float* __restrict__ proj)
{
    __shared__ float rows[ROWS_PER_BLOCK][HH];
    const int r0 = blockIdx.x * ROWS_PER_BLOCK;
    const int k  = threadIdx.x;

    #pragma unroll
    for (int r = 0; r < ROWS_PER_BLOCK; ++r)
        rows[r][k] = inputs[(size_t)(r0 + r) * HH + k];
    __syncthreads();

    float acc[ROWS_PER_BLOCK];
    #pragma unroll
    for (int r = 0; r < ROWS_PER_BLOCK; ++r) acc[r] = 0.f;

    #pragma unroll 8
    for (int h = 0; h < HH; ++h) {
        const float w = W_atom[(size_t)h * HH + k];
        #pragma unroll
        for (int r = 0; r < ROWS_PER_BLOCK; ++r)
            acc[r] = fmaf(rows[r][h], w, acc[r]);
    }

    const float halfb = 0.5f * b_bin[k];
    #pragma unroll
    for (int r = 0; r < ROWS_PER_BLOCK; ++r)
        proj[(size_t)(r0 + r) * HH + k] = acc[r] + halfb;
}

// ---------------------------------------------------------------------------
// Kernel 2a: dedicated streaming writer, tuned for write BW.
//   One block per bi-PAIR (768 blocks), 512 threads = 8 waves; wave w owns
//   j in [12w, 12w+12): each wave streams 12 KB CONTIGUOUS per output row
//   stream (apb0 and apb1), in_j loaded once and used for both i's.
//   Tiny VGPR -> 3 blocks/CU = 24 waves/CU of pure store pressure.
// ---------------------------------------------------------------------------
__global__ __launch_bounds__(512) void pair_writer(
    const float* __restrict__ inputs,
    float* __restrict__ atom_pair)
{
    const int blk  = blockIdx.x;           // 0 .. BB*NN/2-1
    const int b    = blk / (NN / 2);
    const int ip   = blk % (NN / 2);
    const int bi0  = b * NN + 2 * ip;
    const int lane = threadIdx.x & 63;
    const int wave = threadIdx.x >> 6;     // 0..7
    const int k4   = lane << 2;

    const float4 in_i0 = *(const float4*)(inputs + (size_t)bi0 * HH + k4);
    const float4 in_i1 = *(const float4*)(inputs + (size_t)(bi0 + 1) * HH + k4);
    const float* inb   = inputs + (size_t)b * NN * HH + k4;
    float* apb0 = atom_pair + (size_t)bi0 * NN * HH + k4;
    float* apb1 = atom_pair + (size_t)(bi0 + 1) * NN * HH + k4;

    const int j0 = 12 * wave;
    #pragma unroll 4
    for (int t = 0; t < 12; ++t) {
        const int j = j0 + t;
        const float4 in_j = *(const float4*)(inb + (size_t)j * HH);
        f32x4 ap;
        ap.x = in_i0.x + in_j.x;  ap.y = in_i0.y + in_j.y;
        ap.z = in_i0.z + in_j.z;  ap.w = in_i0.w + in_j.w;
        __builtin_nontemporal_store(ap, (f32x4*)(apb0 + (size_t)j * HH));
        ap.x = in_i1.x + in_j.x;  ap.y = in_i1.y + in_j.y;
        ap.z = in_i1.z + in_j.z;  ap.w = in_i1.w + in_j.w;
        __builtin_nontemporal_store(ap, (f32x4*)(apb1 + (size_t)j * HH));
    }
}

// ---------------------------------------------------------------------------
// Kernel 2b: score + context only (R16 compute path, NO bulk stores).
// ---------------------------------------------------------------------------
__global__ __launch_bounds__(256, 4) void score_ctx_kernel(
    const float* __restrict__ inputs,
    const float* __restrict__ bin_features,
    const float* __restrict__ W_bin,
    const float* __restrict__ w_score,
    const float* __restrict__ b_score,
    const float* __restrict__ proj,
    float* __restrict__ context)
{
    const int blk   = blockIdx.x;          // 0 .. BB*NN/IB-1
    const int b     = blk / (NN / IB);
    const int ip    = blk % (NN / IB);
    const int bi0   = b * NN + IB * ip;    // and bi0+1
    const int lane  = threadIdx.x & 63;
    const int wave  = threadIdx.x >> 6;    // 0..3
    const int swave = __builtin_amdgcn_readfirstlane(wave);
    const int k4    = lane << 2;

    __shared__ float partial[3][IB * HH];

    const float4 pr_i0 = *(const float4*)(proj + (size_t)bi0 * HH + k4);
    const float4 pr_i1 = *(const float4*)(proj + (size_t)(bi0 + 1) * HH + k4);
    const float4 ws    = *(const float4*)(w_score + k4);
    const float  bsc   = b_score[0];

    float4 wb[NBIN];
    #pragma unroll
    for (int c = 0; c < NBIN; ++c)
        wb[c] = *(const float4*)(W_bin + c * HH + k4);

    const float* inb  = inputs + (size_t)b * NN * HH + k4;
    const float* prb  = proj   + (size_t)b * NN * HH + k4;

    const float* bin0 = bin_features + (size_t)bi0 * NN * NBIN;
    const float* bin1 = bin_features + (size_t)(bi0 + 1) * NN * NBIN;

    float4 acc0 = make_float4(0.f, 0.f, 0.f, 0.f);
    float4 acc1 = make_float4(0.f, 0.f, 0.f, 0.f);

    for (int t = 0; t < 12; ++t) {
        const int j0 = swave + 8 * t;      // scalar; j's: j0, j0+4

        float4 inj[2], prj[2];
        #pragma unroll
        for (int u = 0; u < 2; ++u) {
            inj[u] = *(const float4*)(inb + (size_t)(j0 + 4 * u) * HH);
            prj[u] = *(const float4*)(prb + (size_t)(j0 + 4 * u) * HH);
        }

        float part[4];                     // [2u+ii]
        #pragma unroll
        for (int u = 0; u < 2; ++u) {
            const int j = j0 + 4 * u;      // scalar
            #pragma unroll
            for (int ii = 0; ii < 2; ++ii) {
                const float* bp = (ii ? bin1 : bin0) + (size_t)j * NBIN;
                const float4 pri = ii ? pr_i1 : pr_i0;
                float4 v;
                v.x = pri.x + prj[u].x;  v.y = pri.y + prj[u].y;
                v.z = pri.z + prj[u].z;  v.w = pri.w + prj[u].w;
                #pragma unroll
                for (int c = 0; c < NBIN; ++c) {
                    const float bc = bp[c];   // SGPR operand
                    v.x = fmaf(bc, wb[c].x, v.x);
                    v.y = fmaf(bc, wb[c].y, v.y);
                    v.z = fmaf(bc, wb[c].z, v.z);
                    v.w = fmaf(bc, wb[c].w, v.w);
                }
                v.x = fmaxf(v.x, 0.f); v.y = fmaxf(v.y, 0.f);
                v.z = fmaxf(v.z, 0.f); v.w = fmaxf(v.w, 0.f);
                part[2 * u + ii] =
                    v.x * ws.x + v.y * ws.y + v.z * ws.z + v.w * ws.w;
            }
        }

        float s[4];
        #pragma unroll
        for (int p = 0; p < 4; ++p) {
            const float tot = wave64_sum_uniform(part[p]);
            s[p] = __builtin_amdgcn_rcpf(1.f + __expf(-(tot + bsc)));
        }

        #pragma unroll
        for (int u = 0; u < 2; ++u) {
            acc0.x = fmaf(s[2 * u],     inj[u].x, acc0.x);
            acc0.y = fmaf(s[2 * u],     inj[u].y, acc0.y);
            acc0.z = fmaf(s[2 * u],     inj[u].z, acc0.z);
            acc0.w = fmaf(s[2 * u],     inj[u].w, acc0.w);
            acc1.x = fmaf(s[2 * u + 1], inj[u].x, acc1.x);
            acc1.y = fmaf(s[2 * u + 1], inj[u].y, acc1.y);
            acc1.z = fmaf(s[2 * u + 1], inj[u].z, acc1.z);
            acc1.w = fmaf(s[2 * u + 1], inj[u].w, acc1.w);
        }
    }

    if (wave > 0) {
        *(float4*)(&partial[wave - 1][k4]) = acc0;
        *(float4*)(&partial[wave - 1][HH + k4]) = acc1;
    }
    __syncthreads();
    if (wave == 0) {
        #pragma unroll
        for (int w = 0; w < 3; ++w) {
            const float4 p0 = *(const float4*)(&partial[w][k4]);
            const float4 p1 = *(const float4*)(&partial[w][HH + k4]);
            acc0.x += p0.x; acc0.y += p0.y; acc0.z += p0.z; acc0.w += p0.w;
            acc1.x += p1.x; acc1.y += p1.y; acc1.z += p1.z; acc1.w += p1.w;
        }
        *(float4*)(context + (size_t)bi0 * HH + k4) = acc0;
        *(float4*)(context + (size_t)(bi0 + 1) * HH + k4) = acc1;
    }
}

extern "C" void kernel_launch(void* const* d_in, const int* in_sizes, int n_in,
                              void* d_out, int out_size, void* d_ws, size_t ws_size,
                              hipStream_t stream)
{
    const float* inputs       = (const float*)d_in[0];   // (B,N,H)
    const float* bin_features = (const float*)d_in[1];   // (B,N,N,BIN)
    const float* W_atom       = (const float*)d_in[2];   // (H,H)
    const float* W_bin        = (const float*)d_in[3];   // (BIN,H)
    const float* b_bin        = (const float*)d_in[4];   // (H,)
    const float* w_score      = (const float*)d_in[5];   // (H,1)
    const float* b_score      = (const float*)d_in[6];   // (1,)

    float* context   = (float*)d_out;                         // B*N*H
    float* atom_pair = (float*)d_out + (size_t)BB * NN * HH;  // B*N*N*H

    float* proj = (float*)d_ws;                               // B*N*H floats

    proj_kernel<<<(BB * NN) / ROWS_PER_BLOCK, HH, 0, stream>>>(
        inputs, W_atom, b_bin, proj);

    pair_writer<<<(BB * NN) / 2, 512, 0, stream>>>(inputs, atom_pair);

    score_ctx_kernel<<<(BB * NN) / IB, 256, 0, stream>>>(
        inputs, bin_features, W_bin, w_score, b_score, proj, context);
}

// Round 19
// 48.305 us; speedup vs baseline: 1.4138x; 1.4138x over previous
//
#include <hip/hip_runtime.h>
#include <math.h>

#define BB 16
#define NN 96
#define HH 256
#define NBIN 11
#define IB 2       // i's per block (load amortization)

typedef float f32x4 __attribute__((ext_vector_type(4)));

// ---------------------------------------------------------------------------
// DPP wave64 sum -> wave-uniform scalar. Pure VALU.
// ---------------------------------------------------------------------------
template <int CTRL>
__device__ __forceinline__ float dpp_add(float x) {
    int t = __builtin_amdgcn_update_dpp(0, __float_as_int(x),
                                        CTRL, 0xf, 0xf, true);
    return x + __int_as_float(t);
}

__device__ __forceinline__ float wave64_sum_uniform(float x) {
    x = dpp_add<0x111>(x);  // row_shr:1
    x = dpp_add<0x112>(x);  // row_shr:2
    x = dpp_add<0x114>(x);  // row_shr:4
    x = dpp_add<0x118>(x);  // row_shr:8
    x = dpp_add<0x142>(x);  // row_bcast:15
    x = dpp_add<0x143>(x);  // row_bcast:31
    return __int_as_float(__builtin_amdgcn_readlane(__float_as_int(x), 63));
}

// ---------------------------------------------------------------------------
// Kernel 1: proj[r][k] = sum_h inputs[r][h] * W_atom[h][k] + 0.5*b_bin[k]
// ---------------------------------------------------------------------------
#define ROWS_PER_BLOCK 3

__global__ __launch_bounds__(HH) void proj_kernel(
    const float* __restrict__ inputs,
    const float* __restrict__ W_atom,
    const float* __restrict__ b_bin,
    float* __restrict__ proj)
{
    __shared__ float rows[ROWS_PER_BLOCK][HH];
    const int r0 = blockIdx.x * ROWS_PER_BLOCK;
    const int k  = threadIdx.x;

    #pragma unroll
    for (int r = 0; r < ROWS_PER_BLOCK; ++r)
        rows[r][k] = inputs[(size_t)(r0 + r) * HH + k];
    __syncthreads();

    float acc[ROWS_PER_BLOCK];
    #pragma unroll
    for (int r = 0; r < ROWS_PER_BLOCK; ++r) acc[r] = 0.f;

    #pragma unroll 8
    for (int h = 0; h < HH; ++h) {
        const float w = W_atom[(size_t)h * HH + k];
        #pragma unroll
        for (int r = 0; r < ROWS_PER_BLOCK; ++r)
            acc[r] = fmaf(rows[r][h], w, acc[r]);
    }

    const float halfb = 0.5f * b_bin[k];
    #pragma unroll
    for (int r = 0; r < ROWS_PER_BLOCK; ++r)
        proj[(size_t)(r0 + r) * HH + k] = acc[r] + halfb;
}

// ---------------------------------------------------------------------------
// Kernel 2 (fused pair + score + context), best-known form (R16):
//   - i-blocked IB=2 (halves inj/prj load traffic)
//   - NT atom_pair stores (write-once stream bypasses L2)
//   - bin rows via wave-uniform scalar loads (SMEM pipe, no LDS staging)
//   - 4 interleaved DPP reduce chains, rcpf sigmoid
//   Fusion is the key mechanism: the 151 MB store stream hides inside the
//   compute path's stall slots (split forms measured strictly worse).
// ---------------------------------------------------------------------------
__global__ __launch_bounds__(256, 4) void pair_ctx_kernel(
    const float* __restrict__ inputs,
    const float* __restrict__ bin_features,
    const float* __restrict__ W_bin,
    const float* __restrict__ w_score,
    const float* __restrict__ b_score,
    const float* __restrict__ proj,
    float* __restrict__ atom_pair,
    float* __restrict__ context)
{
    const int blk   = blockIdx.x;          // 0 .. BB*NN/IB-1
    const int b     = blk / (NN / IB);
    const int ip    = blk % (NN / IB);
    const int bi0   = b * NN + IB * ip;    // and bi0+1
    const int lane  = threadIdx.x & 63;
    const int wave  = threadIdx.x >> 6;    // 0..3
    const int swave = __builtin_amdgcn_readfirstlane(wave);  // scalar copy
    const int k4    = lane << 2;           // float4 offset into H

    __shared__ float partial[3][IB * HH];  // cross-wave context combine only

    const float4 in_i0 = *(const float4*)(inputs + (size_t)bi0 * HH + k4);
    const float4 in_i1 = *(const float4*)(inputs + (size_t)(bi0 + 1) * HH + k4);
    const float4 pr_i0 = *(const float4*)(proj   + (size_t)bi0 * HH + k4);
    const float4 pr_i1 = *(const float4*)(proj   + (size_t)(bi0 + 1) * HH + k4);
    const float4 ws    = *(const float4*)(w_score + k4);
    const float  bsc   = b_score[0];

    float4 wb[NBIN];
    #pragma unroll
    for (int c = 0; c < NBIN; ++c)
        wb[c] = *(const float4*)(W_bin + c * HH + k4);

    const float* inb  = inputs + (size_t)b * NN * HH + k4;
    const float* prb  = proj   + (size_t)b * NN * HH + k4;
    float*       apb0 = atom_pair + (size_t)bi0 * NN * HH + k4;
    float*       apb1 = atom_pair + (size_t)(bi0 + 1) * NN * HH + k4;

    // wave-uniform scalar bases for the two bin row streams
    const float* bin0 = bin_features + (size_t)bi0 * NN * NBIN;
    const float* bin1 = bin_features + (size_t)(bi0 + 1) * NN * NBIN;

    float4 acc0 = make_float4(0.f, 0.f, 0.f, 0.f);
    float4 acc1 = make_float4(0.f, 0.f, 0.f, 0.f);

    // j = swave + 4*u + 8*t, u in {0,1}, t in [0,12) covers [0,96)
    for (int t = 0; t < 12; ++t) {
        const int j0 = swave + 8 * t;      // scalar; j's this step: j0, j0+4

        float4 inj[2], prj[2];
        #pragma unroll
        for (int u = 0; u < 2; ++u) {
            inj[u] = *(const float4*)(inb + (size_t)(j0 + 4 * u) * HH);
            prj[u] = *(const float4*)(prb + (size_t)(j0 + 4 * u) * HH);
        }

        #pragma unroll
        for (int u = 0; u < 2; ++u) {
            f32x4 ap;
            ap.x = in_i0.x + inj[u].x;  ap.y = in_i0.y + inj[u].y;
            ap.z = in_i0.z + inj[u].z;  ap.w = in_i0.w + inj[u].w;
            __builtin_nontemporal_store(
                ap, (f32x4*)(apb0 + (size_t)(j0 + 4 * u) * HH));
            ap.x = in_i1.x + inj[u].x;  ap.y = in_i1.y + inj[u].y;
            ap.z = in_i1.z + inj[u].z;  ap.w = in_i1.w + inj[u].w;
            __builtin_nontemporal_store(
                ap, (f32x4*)(apb1 + (size_t)(j0 + 4 * u) * HH));
        }

        float part[4];                     // [2u+ii]
        #pragma unroll
        for (int u = 0; u < 2; ++u) {
            const int j = j0 + 4 * u;      // scalar
            #pragma unroll
            for (int ii = 0; ii < 2; ++ii) {
                // wave-uniform scalar pointer -> s_load into SGPRs
                const float* bp = (ii ? bin1 : bin0) + (size_t)j * NBIN;

                const float4 pri = ii ? pr_i1 : pr_i0;
                float4 v;
                v.x = pri.x + prj[u].x;  v.y = pri.y + prj[u].y;
                v.z = pri.z + prj[u].z;  v.w = pri.w + prj[u].w;
                #pragma unroll
                for (int c = 0; c < NBIN; ++c) {
                    const float bc = bp[c];   // SGPR operand of v_fma
                    v.x = fmaf(bc, wb[c].x, v.x);
                    v.y = fmaf(bc, wb[c].y, v.y);
                    v.z = fmaf(bc, wb[c].z, v.z);
                    v.w = fmaf(bc, wb[c].w, v.w);
                }
                v.x = fmaxf(v.x, 0.f); v.y = fmaxf(v.y, 0.f);
                v.z = fmaxf(v.z, 0.f); v.w = fmaxf(v.w, 0.f);
                part[2 * u + ii] =
                    v.x * ws.x + v.y * ws.y + v.z * ws.z + v.w * ws.w;
            }
        }

        // four independent DPP reduce chains (2 j x 2 i), pure VALU
        float s[4];
        #pragma unroll
        for (int p = 0; p < 4; ++p) {
            const float tot = wave64_sum_uniform(part[p]);
            s[p] = __builtin_amdgcn_rcpf(1.f + __expf(-(tot + bsc)));
        }

        #pragma unroll
        for (int u = 0; u < 2; ++u) {
            acc0.x = fmaf(s[2 * u],     inj[u].x, acc0.x);
            acc0.y = fmaf(s[2 * u],     inj[u].y, acc0.y);
            acc0.z = fmaf(s[2 * u],     inj[u].z, acc0.z);
            acc0.w = fmaf(s[2 * u],     inj[u].w, acc0.w);
            acc1.x = fmaf(s[2 * u + 1], inj[u].x, acc1.x);
            acc1.y = fmaf(s[2 * u + 1], inj[u].y, acc1.y);
            acc1.z = fmaf(s[2 * u + 1], inj[u].z, acc1.z);
            acc1.w = fmaf(s[2 * u + 1], inj[u].w, acc1.w);
        }
    }

    // cross-wave reduce of both context accumulators
    if (wave > 0) {
        *(float4*)(&partial[wave - 1][k4]) = acc0;
        *(float4*)(&partial[wave - 1][HH + k4]) = acc1;
    }
    __syncthreads();
    if (wave == 0) {
        #pragma unroll
        for (int w = 0; w < 3; ++w) {
            const float4 p0 = *(const float4*)(&partial[w][k4]);
            const float4 p1 = *(const float4*)(&partial[w][HH + k4]);
            acc0.x += p0.x; acc0.y += p0.y; acc0.z += p0.z; acc0.w += p0.w;
            acc1.x += p1.x; acc1.y += p1.y; acc1.z += p1.z; acc1.w += p1.w;
        }
        *(float4*)(context + (size_t)bi0 * HH + k4) = acc0;
        *(float4*)(context + (size_t)(bi0 + 1) * HH + k4) = acc1;
    }
}

extern "C" void kernel_launch(void* const* d_in, const int* in_sizes, int n_in,
                              void* d_out, int out_size, void* d_ws, size_t ws_size,
                              hipStream_t stream)
{
    const float* inputs       = (const float*)d_in[0];   // (B,N,H)
    const float* bin_features = (const float*)d_in[1];   // (B,N,N,BIN)
    const float* W_atom       = (const float*)d_in[2];   // (H,H)
    const float* W_bin        = (const float*)d_in[3];   // (BIN,H)
    const float* b_bin        = (const float*)d_in[4];   // (H,)
    const float* w_score      = (const float*)d_in[5];   // (H,1)
    const float* b_score      = (const float*)d_in[6];   // (1,)

    float* context   = (float*)d_out;                         // B*N*H
    float* atom_pair = (float*)d_out + (size_t)BB * NN * HH;  // B*N*N*H

    float* proj = (float*)d_ws;                               // B*N*H floats

    proj_kernel<<<(BB * NN) / ROWS_PER_BLOCK, HH, 0, stream>>>(
        inputs, W_atom, b_bin, proj);

    pair_ctx_kernel<<<(BB * NN) / IB, 256, 0, stream>>>(
        inputs, bin_features, W_bin, w_score, b_score, proj,
        atom_pair, context);
}